// Round 2
// baseline (119.317 us; speedup 1.0000x reference)
//
#include <hip/hip_runtime.h>

// SoftFAPELoss: B=8, N=M=4096, D=3.
// Single-pass online shifted softmax with deferred rescale (THR=8).
// Each wave owns 64 rows (1 per lane) and scans all 512 staged q's from
// an 8 KB LDS buffer (wave-uniform ds_read_b128 broadcast). No cross-wave
// merge, no mid-kernel barriers. Per (row,q): A = q.p + q.w (3 fma),
// arg = s - A; common path (arg <= 8): w = exp2(arg), L += w,
// S = fma(w, arg, S). Rare path (arg > 8, new min far below shift):
// rescale to s' = A: f = exp2(-arg), S = f*(S - arg*L), L = f*L + 1.
// Invariant: s >= true chunk min, so finalize's dm <= 0 / L >= 1 hold.
// Pg[row*8+ms] = {s + c|p|^2, L, S, 0} - same format as before;
// finalize unchanged.

#define B_    8
#define N_    4096
#define M_    4096
#define NWAVE 8
#define BLOCK 512
#define RPB   512                 // rows per block (64 per wave, 1 per lane)
#define MSPL  8                   // M split across blocks
#define QCH   (M_ / MSPL)         // 512 q per block
#define LOG2E 1.4426950408889634f
#define LN2   0.6931471805599453f
#define BIGF  3.0e38f
#define THR   8.0f

__global__ __launch_bounds__(BLOCK, 4) void softfape_main(
    const float* __restrict__ X_pred, const float* __restrict__ X_true,
    const float* __restrict__ R_pred, const float* __restrict__ t_pred,
    const float* __restrict__ R_true, const float* __restrict__ t_true,
    const float* __restrict__ temp,
    float4* __restrict__ Pg)
{
    __shared__ float4 Q[QCH];            // 8 KB total LDS

    const int tid  = threadIdx.x;
    const int wave = tid >> 6;
    const int lane = tid & 63;
    const int x    = blockIdx.x;
    const int ms   = x & 7;              // M-chunk
    const int rg   = (x >> 3) & 7;       // row group (512 rows each)
    const int b    = x >> 6;             // batch

    const float T   = temp[0];
    const float c   = LOG2E / T;
    const float m2c = -2.0f * c;

    // ---- stage 512 transformed+prescaled q's (threads 0..255, 2 each) ----
    // q.xyz = -2c*y, q.w = c*|y|^2  ->  A = q.p + q.w = c*(|y|^2 - 2 p.y)
    if (tid < QCH / 2) {
        const float g00 = R_true[b*9+0], g01 = R_true[b*9+1], g02 = R_true[b*9+2];
        const float g10 = R_true[b*9+3], g11 = R_true[b*9+4], g12 = R_true[b*9+5];
        const float g20 = R_true[b*9+6], g21 = R_true[b*9+7], g22 = R_true[b*9+8];
        const float u0  = t_true[b*3+0], u1 = t_true[b*3+1], u2 = t_true[b*3+2];
        const float2* xt = (const float2*)(X_true + ((size_t)b * M_ + ms * QCH) * 3);
        const float2 f0 = xt[3*tid+0], f1 = xt[3*tid+1], f2 = xt[3*tid+2];
        {
            const float y0 = fmaf(g00, f0.x, fmaf(g01, f0.y, fmaf(g02, f1.x, u0)));
            const float y1 = fmaf(g10, f0.x, fmaf(g11, f0.y, fmaf(g12, f1.x, u1)));
            const float y2 = fmaf(g20, f0.x, fmaf(g21, f0.y, fmaf(g22, f1.x, u2)));
            const float nn = fmaf(y0, y0, fmaf(y1, y1, y2 * y2));
            Q[2*tid]   = make_float4(m2c*y0, m2c*y1, m2c*y2, c*nn);
        }
        {
            const float y0 = fmaf(g00, f1.y, fmaf(g01, f2.x, fmaf(g02, f2.y, u0)));
            const float y1 = fmaf(g10, f1.y, fmaf(g11, f2.x, fmaf(g12, f2.y, u1)));
            const float y2 = fmaf(g20, f1.y, fmaf(g21, f2.x, fmaf(g22, f2.y, u2)));
            const float nn = fmaf(y0, y0, fmaf(y1, y1, y2 * y2));
            Q[2*tid+1] = make_float4(m2c*y0, m2c*y1, m2c*y2, c*nn);
        }
    }

    // ---- my single row: transformed pred point, pw = c*|p|^2 ----
    float px, py, pz, pw;
    {
        const float h00 = R_pred[b*9+0], h01 = R_pred[b*9+1], h02 = R_pred[b*9+2];
        const float h10 = R_pred[b*9+3], h11 = R_pred[b*9+4], h12 = R_pred[b*9+5];
        const float h20 = R_pred[b*9+6], h21 = R_pred[b*9+7], h22 = R_pred[b*9+8];
        const float v0 = t_pred[b*3+0], v1 = t_pred[b*3+1], v2 = t_pred[b*3+2];
        const int row = rg * RPB + wave * 64 + lane;
        const float* xp = X_pred + ((size_t)b * N_ + row) * 3;
        const float rx = xp[0], ry = xp[1], rz = xp[2];
        px = fmaf(h00, rx, fmaf(h01, ry, fmaf(h02, rz, v0)));
        py = fmaf(h10, rx, fmaf(h11, ry, fmaf(h12, rz, v1)));
        pz = fmaf(h20, rx, fmaf(h21, ry, fmaf(h22, rz, v2)));
        pw = c * fmaf(px, px, fmaf(py, py, pz * pz));
    }

    __syncthreads();   // the only barrier

    // ---- single-pass online scan over all 512 q's ----
    float s = BIGF, L = 0.0f, S = 0.0f;
    for (int k0 = 0; k0 < QCH; k0 += 8) {
        float4 qv[8];
        #pragma unroll
        for (int j = 0; j < 8; ++j) qv[j] = Q[k0 + j];   // wave-uniform broadcast
        #pragma unroll
        for (int j = 0; j < 8; ++j) {
            const float4 q = qv[j];
            const float A   = fmaf(q.x, px, fmaf(q.y, py, fmaf(q.z, pz, q.w)));
            const float arg = s - A;                 // <= THR on common path
            if (arg > THR) {
                // new min far below shift: move shift to s' = A (delta = -arg)
                const float f = __builtin_amdgcn_exp2f(-arg);
                S = f * fmaf(-arg, L, S);            // f*(S + delta*L)
                L = fmaf(L, f, 1.0f);                // f*L + exp2(0)
                s = A;
            } else {
                const float w = __builtin_amdgcn_exp2f(arg);   // <= 2^8
                L += w;
                S = fmaf(w, arg, S);                 // sum w*(s - A)
            }
        }
    }

    // ---- write chunk partial: shift in d-units, L, S ----
    const int row = rg * RPB + wave * 64 + lane;
    const size_t grow = (size_t)b * N_ + row;
    Pg[grow * MSPL + ms] = make_float4(s + pw, L, S, 0.0f);
}

__global__ __launch_bounds__(256) void softfape_finalize(
    const float4* __restrict__ Pg, const float* __restrict__ temp,
    float* __restrict__ out)
{
    __shared__ float ws4[4];
    const int tid = threadIdx.x;
    const size_t row = (size_t)blockIdx.x * 256 + tid;

    float4 P[MSPL];
    #pragma unroll
    for (int i = 0; i < MSPL; ++i) P[i] = Pg[row * MSPL + i];

    float m = P[0].x;
    #pragma unroll
    for (int i = 1; i < MSPL; ++i) m = fminf(m, P[i].x);

    float L = 0.0f, SA = 0.0f;
    #pragma unroll
    for (int i = 0; i < MSPL; ++i) {
        const float dm = m - P[i].x;                    // <= 0
        const float f  = __builtin_amdgcn_exp2f(dm);
        L  = fmaf(P[i].y, f, L);
        SA = fmaf(f, fmaf(dm, P[i].y, P[i].z), SA);
    }
    float wd = m - SA / L;   // = c * weighted_distance(row); L >= 1 guaranteed

    wd += __shfl_xor(wd, 1);  wd += __shfl_xor(wd, 2);  wd += __shfl_xor(wd, 4);
    wd += __shfl_xor(wd, 8);  wd += __shfl_xor(wd, 16); wd += __shfl_xor(wd, 32);
    if ((tid & 63) == 0) ws4[tid >> 6] = wd;
    __syncthreads();
    if (tid == 0) {
        const float s = ws4[0] + ws4[1] + ws4[2] + ws4[3];
        const float scale = temp[0] * LN2 / ((float)B_ * (float)N_);  // 1/c, mean
        atomicAdd(out, s * scale);
    }
}

extern "C" void kernel_launch(void* const* d_in, const int* in_sizes, int n_in,
                              void* d_out, int out_size, void* d_ws, size_t ws_size,
                              hipStream_t stream) {
    const float* X_pred = (const float*)d_in[0];
    const float* X_true = (const float*)d_in[1];
    const float* R_pred = (const float*)d_in[2];
    const float* t_pred = (const float*)d_in[3];
    const float* R_true = (const float*)d_in[4];
    const float* t_true = (const float*)d_in[5];
    const float* temp   = (const float*)d_in[6];
    float* out = (float*)d_out;

    float4* Pg = (float4*)d_ws;   // B*N*MSPL float4 = 4 MB, fully overwritten

    hipMemsetAsync(out, 0, sizeof(float), stream);

    // 512 blocks: b(8) x rowgroup(8) x mchunk(8); 8 waves/block, 1 row/lane
    softfape_main<<<dim3(B_ * (N_ / RPB) * MSPL), BLOCK, 0, stream>>>(
        X_pred, X_true, R_pred, t_pred, R_true, t_true, temp, Pg);

    softfape_finalize<<<dim3((B_ * N_) / 256), 256, 0, stream>>>(Pg, temp, out);
}

// Round 3
// 103.689 us; speedup vs baseline: 1.1507x; 1.1507x over previous
//
#include <hip/hip_runtime.h>

// SoftFAPELoss: B=8, N=M=4096, D=3. Exact two-pass shifted softmax.
// R=8 revision: 512 rows/block (8 per lane), 8 waves split the 512-q chunk
// (64 q each). One wave-uniform ds_read_b128 serves 64 lanes x 8 rows = 512
// pairs -> LDS unit ~25k cyc/CU, well under the ~55k VALU floor (round-2's
// R=1 regression was LDS-unit saturation at ~98k cyc/CU).
// Pass 1 pairs q's: mA = min3(mA, A0, A1) -> 3.5 ops/pair.
// Pass 2: A = q.p + q.w (3 fma), arg = sh - A <= 0, w = exp2(arg),
// L += w, S = fma(w, arg, S). Bit-identical math to the 41 us round-0
// kernel (same per-wave 64-q summation tree; min reassociation exact).
// BLOCK == ROWS == 512: merge phases use all threads, no idle halves.

#define B_    8
#define N_    4096
#define M_    4096
#define NWAVE 8
#define BLOCK 512
#define ROWS  512                 // rows per block (8 per lane)
#define RPL   8                   // rows per lane
#define MSPL  8                   // M split across blocks
#define QCH   (M_ / MSPL)         // 512 q per block
#define WQ    (QCH / NWAVE)       // 64 q per wave
#define LOG2E 1.4426950408889634f
#define LN2   0.6931471805599453f
#define BIGF  3.0e38f

__global__ __launch_bounds__(BLOCK, 4) void softfape_main(
    const float* __restrict__ X_pred, const float* __restrict__ X_true,
    const float* __restrict__ R_pred, const float* __restrict__ t_pred,
    const float* __restrict__ R_true, const float* __restrict__ t_true,
    const float* __restrict__ temp,
    float4* __restrict__ Pg)
{
    __shared__ float4 Q[QCH];            //  8 KB
    __shared__ float  Mp[NWAVE][ROWS];   // 16 KB
    __shared__ float  Lp[NWAVE][ROWS];   // 16 KB
    __shared__ float  Sp[NWAVE][ROWS];   // 16 KB
    __shared__ float  shl[ROWS];         //  2 KB (uniform shift per row)
    __shared__ float  pwl[ROWS];         //  2 KB (c*|p|^2 per row)

    const int tid  = threadIdx.x;
    const int wave = tid >> 6;
    const int lane = tid & 63;
    const int x    = blockIdx.x;
    const int ms   = x & 7;              // M-chunk
    const int rg   = (x >> 3) & 7;       // row group (512 rows)
    const int b    = x >> 6;             // batch

    const float T   = temp[0];
    const float c   = LOG2E / T;
    const float m2c = -2.0f * c;

    // ---- stage 512 transformed+prescaled q's (threads 0..255, 2 each) ----
    // q.xyz = -2c*y, q.w = c*|y|^2  ->  A = q.p + q.w = c*(|y|^2 - 2 p.y)
    if (tid < QCH / 2) {
        const float g00 = R_true[b*9+0], g01 = R_true[b*9+1], g02 = R_true[b*9+2];
        const float g10 = R_true[b*9+3], g11 = R_true[b*9+4], g12 = R_true[b*9+5];
        const float g20 = R_true[b*9+6], g21 = R_true[b*9+7], g22 = R_true[b*9+8];
        const float u0  = t_true[b*3+0], u1 = t_true[b*3+1], u2 = t_true[b*3+2];
        const float2* xt = (const float2*)(X_true + ((size_t)b * M_ + ms * QCH) * 3);
        const float2 f0 = xt[3*tid+0], f1 = xt[3*tid+1], f2 = xt[3*tid+2];
        {
            const float y0 = fmaf(g00, f0.x, fmaf(g01, f0.y, fmaf(g02, f1.x, u0)));
            const float y1 = fmaf(g10, f0.x, fmaf(g11, f0.y, fmaf(g12, f1.x, u1)));
            const float y2 = fmaf(g20, f0.x, fmaf(g21, f0.y, fmaf(g22, f1.x, u2)));
            const float nn = fmaf(y0, y0, fmaf(y1, y1, y2 * y2));
            Q[2*tid]   = make_float4(m2c*y0, m2c*y1, m2c*y2, c*nn);
        }
        {
            const float y0 = fmaf(g00, f1.y, fmaf(g01, f2.x, fmaf(g02, f2.y, u0)));
            const float y1 = fmaf(g10, f1.y, fmaf(g11, f2.x, fmaf(g12, f2.y, u1)));
            const float y2 = fmaf(g20, f1.y, fmaf(g21, f2.x, fmaf(g22, f2.y, u2)));
            const float nn = fmaf(y0, y0, fmaf(y1, y1, y2 * y2));
            Q[2*tid+1] = make_float4(m2c*y0, m2c*y1, m2c*y2, c*nn);
        }
    }

    // ---- my 8 rows: transformed pred points, pw = c*|p|^2 ----
    // Rows are block-redundant across waves (every wave holds the same 512).
    float px[RPL], py[RPL], pz[RPL];
    {
        const float h00 = R_pred[b*9+0], h01 = R_pred[b*9+1], h02 = R_pred[b*9+2];
        const float h10 = R_pred[b*9+3], h11 = R_pred[b*9+4], h12 = R_pred[b*9+5];
        const float h20 = R_pred[b*9+6], h21 = R_pred[b*9+7], h22 = R_pred[b*9+8];
        const float v0 = t_pred[b*3+0], v1 = t_pred[b*3+1], v2 = t_pred[b*3+2];
        const float4* xp = (const float4*)(X_pred + ((size_t)b * N_ + rg * ROWS + lane * RPL) * 3);
        float f[24];
        #pragma unroll
        for (int i = 0; i < 6; ++i) *(float4*)&f[4*i] = xp[i];
        #pragma unroll
        for (int r = 0; r < RPL; ++r) {
            const float rx = f[3*r], ry = f[3*r+1], rz = f[3*r+2];
            px[r] = fmaf(h00, rx, fmaf(h01, ry, fmaf(h02, rz, v0)));
            py[r] = fmaf(h10, rx, fmaf(h11, ry, fmaf(h12, rz, v1)));
            pz[r] = fmaf(h20, rx, fmaf(h21, ry, fmaf(h22, rz, v2)));
            const float pw = c * fmaf(px[r], px[r], fmaf(py[r], py[r], pz[r] * pz[r]));
            pwl[RPL*lane + r] = pw;   // same value from all waves: benign
        }
    }

    __syncthreads();

    const float4* __restrict__ Qw = Q + wave * WQ;

    // ---- pass 1: min of A over my 64-q slice (min3-paired: 3.5 ops/pair) ----
    float mA[RPL];
    #pragma unroll
    for (int r = 0; r < RPL; ++r) mA[r] = BIGF;
    for (int k0 = 0; k0 < WQ; k0 += 8) {
        float4 qv[8];
        #pragma unroll
        for (int j = 0; j < 8; ++j) qv[j] = Qw[k0 + j];   // wave-uniform broadcast
        #pragma unroll
        for (int j2 = 0; j2 < 4; ++j2) {
            const float4 q0 = qv[2*j2], q1 = qv[2*j2+1];
            #pragma unroll
            for (int r = 0; r < RPL; ++r) {
                const float A0 = fmaf(q0.x, px[r], fmaf(q0.y, py[r], fmaf(q0.z, pz[r], q0.w)));
                const float A1 = fmaf(q1.x, px[r], fmaf(q1.y, py[r], fmaf(q1.z, pz[r], q1.w)));
                mA[r] = fminf(mA[r], fminf(A0, A1));   // -> v_min3_f32
            }
        }
    }
    *(float4*)&Mp[wave][RPL*lane]     = make_float4(mA[0], mA[1], mA[2], mA[3]);
    *(float4*)&Mp[wave][RPL*lane + 4] = make_float4(mA[4], mA[5], mA[6], mA[7]);
    __syncthreads();

    // ---- block-uniform per-row shift (all 512 threads, 1 row each) ----
    {
        float m = Mp[0][tid];
        #pragma unroll
        for (int w2 = 1; w2 < NWAVE; ++w2) m = fminf(m, Mp[w2][tid]);
        shl[tid] = m;
    }
    __syncthreads();

    float sh[RPL];
    {
        const float4 s0 = *(const float4*)&shl[RPL*lane];
        const float4 s1 = *(const float4*)&shl[RPL*lane + 4];
        sh[0]=s0.x; sh[1]=s0.y; sh[2]=s0.z; sh[3]=s0.w;
        sh[4]=s1.x; sh[5]=s1.y; sh[6]=s1.z; sh[7]=s1.w;
    }

    // ---- pass 2: shifted sums (7 ops/pair incl. exp) ----
    float L[RPL], S[RPL];
    #pragma unroll
    for (int r = 0; r < RPL; ++r) { L[r] = 0.0f; S[r] = 0.0f; }
    for (int k0 = 0; k0 < WQ; k0 += 8) {
        float4 qv[8];
        #pragma unroll
        for (int j = 0; j < 8; ++j) qv[j] = Qw[k0 + j];
        #pragma unroll
        for (int j = 0; j < 8; ++j) {
            const float4 q = qv[j];
            #pragma unroll
            for (int r = 0; r < RPL; ++r) {
                const float A   = fmaf(q.x, px[r], fmaf(q.y, py[r], fmaf(q.z, pz[r], q.w)));
                const float arg = shl ? (sh[r] - A) : 0.0f;       // <= 0
                const float w   = __builtin_amdgcn_exp2f(sh[r] - A);
                L[r] += w;
                (void)arg;
                S[r] = fmaf(w, sh[r] - A, S[r]);                  // sum w*(m - A)
            }
        }
    }
    *(float4*)&Lp[wave][RPL*lane]     = make_float4(L[0], L[1], L[2], L[3]);
    *(float4*)&Lp[wave][RPL*lane + 4] = make_float4(L[4], L[5], L[6], L[7]);
    *(float4*)&Sp[wave][RPL*lane]     = make_float4(S[0], S[1], S[2], S[3]);
    *(float4*)&Sp[wave][RPL*lane + 4] = make_float4(S[4], S[5], S[6], S[7]);
    __syncthreads();

    // ---- merge 8 wave-partials per row (same shift -> plain adds) ----
    {
        float Lr = 0.0f, Sr = 0.0f;
        #pragma unroll
        for (int w2 = 0; w2 < NWAVE; ++w2) { Lr += Lp[w2][tid]; Sr += Sp[w2][tid]; }
        const size_t row = (size_t)b * N_ + rg * ROWS + tid;
        // m_d = chunk-min of d = minA + pw (d-units); L = sum exp2(m_d - d);
        // SA = sum w*(m_d - d)
        Pg[row * MSPL + ms] = make_float4(shl[tid] + pwl[tid], Lr, Sr, 0.0f);
    }
}

__global__ __launch_bounds__(256) void softfape_finalize(
    const float4* __restrict__ Pg, const float* __restrict__ temp,
    float* __restrict__ out)
{
    __shared__ float ws4[4];
    const int tid = threadIdx.x;
    const size_t row = (size_t)blockIdx.x * 256 + tid;

    float4 P[MSPL];
    #pragma unroll
    for (int i = 0; i < MSPL; ++i) P[i] = Pg[row * MSPL + i];

    float m = P[0].x;
    #pragma unroll
    for (int i = 1; i < MSPL; ++i) m = fminf(m, P[i].x);

    float L = 0.0f, SA = 0.0f;
    #pragma unroll
    for (int i = 0; i < MSPL; ++i) {
        const float dm = m - P[i].x;                    // <= 0
        const float f  = __builtin_amdgcn_exp2f(dm);
        L  = fmaf(P[i].y, f, L);
        SA = fmaf(f, fmaf(dm, P[i].y, P[i].z), SA);
    }
    float wd = m - SA / L;   // = c * weighted_distance(row); L >= 1 guaranteed

    wd += __shfl_xor(wd, 1);  wd += __shfl_xor(wd, 2);  wd += __shfl_xor(wd, 4);
    wd += __shfl_xor(wd, 8);  wd += __shfl_xor(wd, 16); wd += __shfl_xor(wd, 32);
    if ((tid & 63) == 0) ws4[tid >> 6] = wd;
    __syncthreads();
    if (tid == 0) {
        const float s = ws4[0] + ws4[1] + ws4[2] + ws4[3];
        const float scale = temp[0] * LN2 / ((float)B_ * (float)N_);  // 1/c, mean
        atomicAdd(out, s * scale);
    }
}

extern "C" void kernel_launch(void* const* d_in, const int* in_sizes, int n_in,
                              void* d_out, int out_size, void* d_ws, size_t ws_size,
                              hipStream_t stream) {
    const float* X_pred = (const float*)d_in[0];
    const float* X_true = (const float*)d_in[1];
    const float* R_pred = (const float*)d_in[2];
    const float* t_pred = (const float*)d_in[3];
    const float* R_true = (const float*)d_in[4];
    const float* t_true = (const float*)d_in[5];
    const float* temp   = (const float*)d_in[6];
    float* out = (float*)d_out;

    float4* Pg = (float4*)d_ws;   // B*N*MSPL float4 = 4 MB, fully overwritten

    hipMemsetAsync(out, 0, sizeof(float), stream);

    // 512 blocks: b(8) x rowgroup(8) x mchunk(8); 8 waves, 8 rows/lane
    softfape_main<<<dim3(B_ * (N_ / ROWS) * MSPL), BLOCK, 0, stream>>>(
        X_pred, X_true, R_pred, t_pred, R_true, t_true, temp, Pg);

    softfape_finalize<<<dim3((B_ * N_) / 256), 256, 0, stream>>>(Pg, temp, out);
}

// Round 4
// 95.746 us; speedup vs baseline: 1.2462x; 1.0830x over previous
//
#include <hip/hip_runtime.h>

// SoftFAPELoss: B=8, N=M=4096, D=3. Single-pass UNSHIFTED softmax.
// Insight: the softmax shift need not be the chunk min -- it only must keep
// exp2 in range. With per-row shift sh = -c|p|^2 (register), arg = sh - A =
// -c*d^2 <= 0: overflow impossible. Power-of-2 shifts are EXACT in f32, so
// unshifted accumulation has the same relative precision as min-shifted
// as long as c*d^2_min < ~120 (clouds overlap; d^2_min << 1 here).
// Safety net for total underflow (all weights flush to 0 -> L=0): track
// mx = max(arg) = -c*d^2_min per row (0.5 slots/pair via v_max3) and store
// in partial .w; finalize uses wd = -mx iff L == 0 (softmax ~= argmin).
// Cost: 10.5 slot-equivalents/pair (was 13.5 two-pass): 3 fma + sub +
// add + fma + 0.5 max3 + quarter-rate exp. Pass-1 loop, its LDS reads,
// the min-merge barrier and shl/pwl buffers are all deleted.
// Chunk shift in d-units is the constant 0 -> Pg = {0, L, S, mx};
// finalize merge math unchanged (m = 0, f = 1) + L==0 fallback.

#define B_    8
#define N_    4096
#define M_    4096
#define NWAVE 8
#define BLOCK 512
#define ROWS  512                 // rows per block (8 per lane)
#define RPL   8                   // rows per lane
#define MSPL  8                   // M split across blocks
#define QCH   (M_ / MSPL)         // 512 q per block
#define WQ    (QCH / NWAVE)       // 64 q per wave
#define LOG2E 1.4426950408889634f
#define LN2   0.6931471805599453f
#define NEGBIG -3.0e38f

__global__ __launch_bounds__(BLOCK, 4) void softfape_main(
    const float* __restrict__ X_pred, const float* __restrict__ X_true,
    const float* __restrict__ R_pred, const float* __restrict__ t_pred,
    const float* __restrict__ R_true, const float* __restrict__ t_true,
    const float* __restrict__ temp,
    float4* __restrict__ Pg)
{
    __shared__ float4 Q[QCH];            //  8 KB
    __shared__ float  Lp[NWAVE][ROWS];   // 16 KB
    __shared__ float  Sp[NWAVE][ROWS];   // 16 KB
    __shared__ float  Mp[NWAVE][ROWS];   // 16 KB (per-wave max arg per row)

    const int tid  = threadIdx.x;
    const int wave = tid >> 6;
    const int lane = tid & 63;
    const int x    = blockIdx.x;
    const int ms   = x & 7;              // M-chunk
    const int rg   = (x >> 3) & 7;       // row group (512 rows)
    const int b    = x >> 6;             // batch

    const float T   = temp[0];
    const float c   = LOG2E / T;
    const float m2c = -2.0f * c;

    // ---- stage 512 transformed+prescaled q's (threads 0..255, 2 each) ----
    // q.xyz = -2c*y, q.w = c*|y|^2  ->  A = q.p + q.w = c*(|y|^2 - 2 p.y)
    if (tid < QCH / 2) {
        const float g00 = R_true[b*9+0], g01 = R_true[b*9+1], g02 = R_true[b*9+2];
        const float g10 = R_true[b*9+3], g11 = R_true[b*9+4], g12 = R_true[b*9+5];
        const float g20 = R_true[b*9+6], g21 = R_true[b*9+7], g22 = R_true[b*9+8];
        const float u0  = t_true[b*3+0], u1 = t_true[b*3+1], u2 = t_true[b*3+2];
        const float2* xt = (const float2*)(X_true + ((size_t)b * M_ + ms * QCH) * 3);
        const float2 f0 = xt[3*tid+0], f1 = xt[3*tid+1], f2 = xt[3*tid+2];
        {
            const float y0 = fmaf(g00, f0.x, fmaf(g01, f0.y, fmaf(g02, f1.x, u0)));
            const float y1 = fmaf(g10, f0.x, fmaf(g11, f0.y, fmaf(g12, f1.x, u1)));
            const float y2 = fmaf(g20, f0.x, fmaf(g21, f0.y, fmaf(g22, f1.x, u2)));
            const float nn = fmaf(y0, y0, fmaf(y1, y1, y2 * y2));
            Q[2*tid]   = make_float4(m2c*y0, m2c*y1, m2c*y2, c*nn);
        }
        {
            const float y0 = fmaf(g00, f1.y, fmaf(g01, f2.x, fmaf(g02, f2.y, u0)));
            const float y1 = fmaf(g10, f1.y, fmaf(g11, f2.x, fmaf(g12, f2.y, u1)));
            const float y2 = fmaf(g20, f1.y, fmaf(g21, f2.x, fmaf(g22, f2.y, u2)));
            const float nn = fmaf(y0, y0, fmaf(y1, y1, y2 * y2));
            Q[2*tid+1] = make_float4(m2c*y0, m2c*y1, m2c*y2, c*nn);
        }
    }

    // ---- my 8 rows: transformed pred points; sh[r] = -c*|p|^2 (register) ----
    float px[RPL], py[RPL], pz[RPL], sh[RPL];
    {
        const float h00 = R_pred[b*9+0], h01 = R_pred[b*9+1], h02 = R_pred[b*9+2];
        const float h10 = R_pred[b*9+3], h11 = R_pred[b*9+4], h12 = R_pred[b*9+5];
        const float h20 = R_pred[b*9+6], h21 = R_pred[b*9+7], h22 = R_pred[b*9+8];
        const float v0 = t_pred[b*3+0], v1 = t_pred[b*3+1], v2 = t_pred[b*3+2];
        const float4* xp = (const float4*)(X_pred + ((size_t)b * N_ + rg * ROWS + lane * RPL) * 3);
        float f[24];
        #pragma unroll
        for (int i = 0; i < 6; ++i) *(float4*)&f[4*i] = xp[i];
        #pragma unroll
        for (int r = 0; r < RPL; ++r) {
            const float rx = f[3*r], ry = f[3*r+1], rz = f[3*r+2];
            px[r] = fmaf(h00, rx, fmaf(h01, ry, fmaf(h02, rz, v0)));
            py[r] = fmaf(h10, rx, fmaf(h11, ry, fmaf(h12, rz, v1)));
            pz[r] = fmaf(h20, rx, fmaf(h21, ry, fmaf(h22, rz, v2)));
            sh[r] = -c * fmaf(px[r], px[r], fmaf(py[r], py[r], pz[r] * pz[r]));
        }
    }

    __syncthreads();   // Q ready

    const float4* __restrict__ Qw = Q + wave * WQ;

    // ---- single pass: arg = sh - A = -c*d^2 <= 0 ----
    float L[RPL], S[RPL], mx[RPL];
    #pragma unroll
    for (int r = 0; r < RPL; ++r) { L[r] = 0.0f; S[r] = 0.0f; mx[r] = NEGBIG; }
    for (int k0 = 0; k0 < WQ; k0 += 8) {
        float4 qv[8];
        #pragma unroll
        for (int j = 0; j < 8; ++j) qv[j] = Qw[k0 + j];   // wave-uniform broadcast
        #pragma unroll
        for (int j2 = 0; j2 < 4; ++j2) {
            const float4 q0 = qv[2*j2], q1 = qv[2*j2+1];
            #pragma unroll
            for (int r = 0; r < RPL; ++r) {
                const float A0   = fmaf(q0.x, px[r], fmaf(q0.y, py[r], fmaf(q0.z, pz[r], q0.w)));
                const float A1   = fmaf(q1.x, px[r], fmaf(q1.y, py[r], fmaf(q1.z, pz[r], q1.w)));
                const float arg0 = sh[r] - A0;
                const float arg1 = sh[r] - A1;
                const float w0   = __builtin_amdgcn_exp2f(arg0);
                const float w1   = __builtin_amdgcn_exp2f(arg1);
                L[r] += w0;
                L[r] += w1;
                S[r]  = fmaf(w0, arg0, S[r]);
                S[r]  = fmaf(w1, arg1, S[r]);
                mx[r] = fmaxf(fmaxf(mx[r], arg0), arg1);   // -> v_max3_f32
            }
        }
    }
    *(float4*)&Lp[wave][RPL*lane]     = make_float4(L[0], L[1], L[2], L[3]);
    *(float4*)&Lp[wave][RPL*lane + 4] = make_float4(L[4], L[5], L[6], L[7]);
    *(float4*)&Sp[wave][RPL*lane]     = make_float4(S[0], S[1], S[2], S[3]);
    *(float4*)&Sp[wave][RPL*lane + 4] = make_float4(S[4], S[5], S[6], S[7]);
    *(float4*)&Mp[wave][RPL*lane]     = make_float4(mx[0], mx[1], mx[2], mx[3]);
    *(float4*)&Mp[wave][RPL*lane + 4] = make_float4(mx[4], mx[5], mx[6], mx[7]);
    __syncthreads();

    // ---- merge 8 wave-partials per row (same shift 0 -> plain adds) ----
    {
        float Lr = 0.0f, Sr = 0.0f, mw = Mp[0][tid];
        #pragma unroll
        for (int w2 = 0; w2 < NWAVE; ++w2) { Lr += Lp[w2][tid]; Sr += Sp[w2][tid]; }
        #pragma unroll
        for (int w2 = 1; w2 < NWAVE; ++w2) mw = fmaxf(mw, Mp[w2][tid]);
        const size_t row = (size_t)b * N_ + rg * ROWS + tid;
        // shift in d-units = 0 exactly; mx = -c*d^2_min for underflow fallback
        Pg[row * MSPL + ms] = make_float4(0.0f, Lr, Sr, mw);
    }
}

__global__ __launch_bounds__(256) void softfape_finalize(
    const float4* __restrict__ Pg, const float* __restrict__ temp,
    float* __restrict__ out)
{
    __shared__ float ws4[4];
    const int tid = threadIdx.x;
    const size_t row = (size_t)blockIdx.x * 256 + tid;

    float4 P[MSPL];
    #pragma unroll
    for (int i = 0; i < MSPL; ++i) P[i] = Pg[row * MSPL + i];

    float m = P[0].x;
    float mw = P[0].w;
    #pragma unroll
    for (int i = 1; i < MSPL; ++i) { m = fminf(m, P[i].x); mw = fmaxf(mw, P[i].w); }

    float L = 0.0f, SA = 0.0f;
    #pragma unroll
    for (int i = 0; i < MSPL; ++i) {
        const float dm = m - P[i].x;                    // <= 0 (all zero here)
        const float f  = __builtin_amdgcn_exp2f(dm);
        L  = fmaf(P[i].y, f, L);
        SA = fmaf(f, fmaf(dm, P[i].y, P[i].z), SA);
    }
    // wd = c * weighted_distance(row). If every weight flushed to zero
    // (c*d^2_min > ~126, never on this data), softmax ~= argmin: wd = -mw.
    float wd = (L > 0.0f) ? (m - SA / L) : -mw;

    wd += __shfl_xor(wd, 1);  wd += __shfl_xor(wd, 2);  wd += __shfl_xor(wd, 4);
    wd += __shfl_xor(wd, 8);  wd += __shfl_xor(wd, 16); wd += __shfl_xor(wd, 32);
    if ((tid & 63) == 0) ws4[tid >> 6] = wd;
    __syncthreads();
    if (tid == 0) {
        const float s = ws4[0] + ws4[1] + ws4[2] + ws4[3];
        const float scale = temp[0] * LN2 / ((float)B_ * (float)N_);  // 1/c, mean
        atomicAdd(out, s * scale);
    }
}

extern "C" void kernel_launch(void* const* d_in, const int* in_sizes, int n_in,
                              void* d_out, int out_size, void* d_ws, size_t ws_size,
                              hipStream_t stream) {
    const float* X_pred = (const float*)d_in[0];
    const float* X_true = (const float*)d_in[1];
    const float* R_pred = (const float*)d_in[2];
    const float* t_pred = (const float*)d_in[3];
    const float* R_true = (const float*)d_in[4];
    const float* t_true = (const float*)d_in[5];
    const float* temp   = (const float*)d_in[6];
    float* out = (float*)d_out;

    float4* Pg = (float4*)d_ws;   // B*N*MSPL float4 = 4 MB, fully overwritten

    hipMemsetAsync(out, 0, sizeof(float), stream);

    // 512 blocks: b(8) x rowgroup(8) x mchunk(8); 8 waves, 8 rows/lane
    softfape_main<<<dim3(B_ * (N_ / ROWS) * MSPL), BLOCK, 0, stream>>>(
        X_pred, X_true, R_pred, t_pred, R_true, t_true, temp, Pg);

    softfape_finalize<<<dim3((B_ * N_) / 256), 256, 0, stream>>>(Pg, temp, out);
}